// Round 17
// baseline (157.327 us; speedup 1.0000x reference)
//
#include <hip/hip_runtime.h>
#include <stdint.h>

#define B_ 32
#define S_ 32
#define P_ 2048
#define J_ 32
#define I_ 16
#define STILE 8

// U layout: single-b rows. U[b][s][p][jp] dwords, jp = j-pair (16/row).
#define UROW 16
#define UBSTRIDE ((size_t)S_ * P_ * UROW)   // per-b plane = 4 MiB

typedef _Float16 half8_t __attribute__((ext_vector_type(8)));
typedef float f32x16 __attribute__((ext_vector_type(16)));
typedef uint32_t u32x4 __attribute__((ext_vector_type(4)));

// fp16 unpack helpers (dword = {lo: j=2k, hi: j=2k+1} of one b-row)
__device__ inline float f16lo(uint32_t d) {
    return (float)__builtin_bit_cast(_Float16, (unsigned short)(d & 0xffffu));
}
__device__ inline float f16hi(uint32_t d) {
    return (float)__builtin_bit_cast(_Float16, (unsigned short)(d >> 16));
}

// LDS slab physical index: [b][row16][col16] with XOR swizzle.
// row = p ^ (b&1)  (spreads write row-parity by lane parity -> 2-way, free)
// col = jp ^ ((p&3)<<2)  (4-aligned XOR keeps b128 reads contiguous)
__device__ inline int slab_idx(int b, int p, int jp) {
    return b * 256 + ((p ^ (b & 1)) << 4) + (jp ^ ((p & 3) << 2));
}

// =====================================================================
// Kernel 1 (MFMA, s-tiled): per (s,p), C[b=32,j=32] = X[b,:].W[j,:]^T.
// Ladder of proven facts: L2 write-allocate wall -> NT stores (R13);
// NT data + normal loads reads fine (R15 warm: routing 24us); sc0sc1
// stores INCOHERENT with cached loads (R16 fail, reverted). Remaining
// uhat variable = store segment size: 256B segs -> 78us, 32KB linear ->
// 31us (R13). THIS ROUND: block-level LDS transpose so each wave emits
// ONE 1KB-contiguous NT store per (b,s) (32 x 1KB per s-iter) into the
// routing-friendly [b][s][p][jp] layout.
// =====================================================================
__global__ __launch_bounds__(256) void uhat_kernel(
        const float* __restrict__ W, const float* __restrict__ X,
        uint32_t* __restrict__ U) {
    const int tid  = threadIdx.x;
    const int lane = tid & 63;
    const int wave = tid >> 6;
    const int l31  = lane & 31;
    const int lhi  = lane >> 5;       // 0/1
    const int lpar = lane & 1;        // row-parity this lane emits
    const int sb   = blockIdx.y * STILE;
    const int p0b  = blockIdx.x * 16;             // block p-base
    const int p0   = p0b + wave * 4;              // this wave's p-base

    // block-level transpose slab: [32 b][16 p][16 jp] dwords = 32KB
    __shared__ uint32_t slab[8192];

    // ---- X fragments: s-independent. Load + cvt ONCE. ----
    half8_t xh[4];
    #pragma unroll
    for (int t = 0; t < 4; ++t) {
        const float* xr = X + ((size_t)l31 * P_ + (p0 + t)) * I_ + lhi * 8;
        float4 x0 = *reinterpret_cast<const float4*>(xr);
        float4 x1 = *reinterpret_cast<const float4*>(xr + 4);
        xh[t][0] = (_Float16)x0.x; xh[t][1] = (_Float16)x0.y;
        xh[t][2] = (_Float16)x0.z; xh[t][3] = (_Float16)x0.w;
        xh[t][4] = (_Float16)x1.x; xh[t][5] = (_Float16)x1.y;
        xh[t][6] = (_Float16)x1.z; xh[t][7] = (_Float16)x1.w;
    }

    const int g   = l31 >> 1;         // jpair index 0..15
    const int pr  = lane >> 2;        // store-phase: p-row 0..15
    const int jp0 = (lane & 3) << 2;  // store-phase: jp quad base

    // ---- W double buffer (registers) ----
    float4 wv[2][4][2];
    #pragma unroll
    for (int t = 0; t < 4; ++t) {
        const float* wr = W + (((size_t)sb * P_ + (p0 + t)) * J_ + l31) * I_ + lhi * 8;
        wv[0][t][0] = *reinterpret_cast<const float4*>(wr);
        wv[0][t][1] = *reinterpret_cast<const float4*>(wr + 4);
    }

    for (int ss = 0; ss < STILE; ++ss) {
        const int cur = ss & 1, nxt = cur ^ 1;
        if (ss + 1 < STILE) {         // prefetch W for s+1
            #pragma unroll
            for (int t = 0; t < 4; ++t) {
                const float* wr = W + (((size_t)(sb + ss + 1) * P_ + (p0 + t)) * J_
                                        + l31) * I_ + lhi * 8;
                wv[nxt][t][0] = *reinterpret_cast<const float4*>(wr);
                wv[nxt][t][1] = *reinterpret_cast<const float4*>(wr + 4);
            }
        }
        const int s = sb + ss;

        #pragma unroll
        for (int t = 0; t < 4; ++t) {
            const int pl = wave * 4 + t;          // p_local 0..15
            half8_t Bf;
            Bf[0] = (_Float16)wv[cur][t][0].x; Bf[1] = (_Float16)wv[cur][t][0].y;
            Bf[2] = (_Float16)wv[cur][t][0].z; Bf[3] = (_Float16)wv[cur][t][0].w;
            Bf[4] = (_Float16)wv[cur][t][1].x; Bf[5] = (_Float16)wv[cur][t][1].y;
            Bf[6] = (_Float16)wv[cur][t][1].z; Bf[7] = (_Float16)wv[cur][t][1].w;

            f32x16 acc = {};
            acc = __builtin_amdgcn_mfma_f32_32x32x16_f16(xh[t], Bf, acc, 0, 0, 0);

            // pack rows (r,r+1)=(b0,b0+1) at col j=l31 into single-b dwords
            // (R9-proven) and write to swizzled block slab
            #pragma unroll
            for (int m = 0; m < 8; ++m) {
                const int r = 2 * m;
                uint32_t lo16 = (uint32_t)__builtin_bit_cast(
                    unsigned short, (_Float16)acc[r]);       // b0   (RNE)
                uint32_t hi16 = (uint32_t)__builtin_bit_cast(
                    unsigned short, (_Float16)acc[r + 1]);   // b0+1 (RNE)
                uint32_t hp = lo16 | (hi16 << 16);
                uint32_t tp = (uint32_t)__shfl_xor((int)hp, 1, 64);
                uint32_t d = lpar ? ((tp >> 16) | (hp & 0xffff0000u))
                                  : ((hp & 0xffffu) | (tp << 16));
                const int b = (r & 3) + lpar + 8 * (r >> 2) + 4 * lhi;
                slab[slab_idx(b, pl, g)] = d;
            }
        }
        __syncthreads();

        // ---- store phase: wave emits one 1KB-contiguous NT store per b
        // (8 rounds x 4 waves = 32 b). Lane l covers (p=l>>2, jp=(l&3)*4).
        #pragma unroll
        for (int i = 0; i < 8; ++i) {
            const int b = wave * 8 + i;
            u32x4 vv = *reinterpret_cast<const u32x4*>(
                &slab[slab_idx(b, pr, jp0)]);
            __builtin_nontemporal_store(vv, reinterpret_cast<u32x4*>(
                U + (size_t)b * UBSTRIDE + ((size_t)s * P_ + p0b) * UROW
                  + lane * 4));
        }
        __syncthreads();
    }
}

// ---------- split-butterfly wave reduction of a 32-vector ----------
template <int MASK, int HALF>
__device__ inline void red_level(float* red, int lane) {
    const bool hi = (lane & MASK) != 0;
    #pragma unroll
    for (int k = 0; k < HALF; ++k) {
        float send = hi ? red[k] : red[k + HALF];
        float recv = __shfl_xor(send, MASK, 64);
        red[k] = (hi ? red[k + HALF] : red[k]) + recv;
    }
}

// =====================================================================
// Kernel 2: dynamic routing. One 1024-thread block per (b,s) — R5's
// proven structure, R15-verified ~24us warm. Thread owns p-rows 2*tid,
// 2*tid+1: 32 dwords = 128B contiguous, NORMAL loads.
// =====================================================================
__global__ __launch_bounds__(1024) void routing_kernel(
        const uint32_t* __restrict__ U, float* __restrict__ out) {
    const int tid  = threadIdx.x;
    const int lane = tid & 63;
    const int wid  = tid >> 6;            // 0..15
    const int bs   = blockIdx.x;          // b*S_ + s

    __shared__ float sred[16 * 32];       // per-wave 32-vector partials
    __shared__ float vlds[32];
    __shared__ float scal[32];            // [0..15] max, [16..31] sum

    // load my 2 rows: 32 dwords = 128B contiguous (normal loads)
    const uint4* ub = reinterpret_cast<const uint4*>(
        U + (size_t)bs * ((size_t)P_ * UROW) + (size_t)tid * 32);
    uint32_t a[32];
    #pragma unroll
    for (int k = 0; k < 8; ++k) {
        uint4 t = ub[k];
        a[k * 4 + 0] = t.x; a[k * 4 + 1] = t.y;
        a[k * 4 + 2] = t.z; a[k * 4 + 3] = t.w;
    }
    // a[0..15] = row p0 (j-pair dwords), a[16..31] = row p1

    float bp0 = 0.0f, bp1 = 0.0f;         // routing logits for my two p's

    for (int it = 0; it < 3; ++it) {
        // ---- c = softmax(b) over p ----
        float c0, c1;
        if (it == 0) {
            c0 = c1 = 1.0f / 2048.0f;     // softmax of zeros, exact
        } else {
            float mx = fmaxf(bp0, bp1);
            #pragma unroll
            for (int msk = 32; msk >= 1; msk >>= 1)
                mx = fmaxf(mx, __shfl_xor(mx, msk, 64));
            if (lane == 0) scal[wid] = mx;
            __syncthreads();
            mx = scal[0];
            #pragma unroll
            for (int w2 = 1; w2 < 16; ++w2) mx = fmaxf(mx, scal[w2]);
            float e0 = __expf(bp0 - mx);
            float e1 = __expf(bp1 - mx);
            float zs = e0 + e1;
            #pragma unroll
            for (int msk = 32; msk >= 1; msk >>= 1)
                zs += __shfl_xor(zs, msk, 64);
            if (lane == 0) scal[16 + wid] = zs;
            __syncthreads();
            float Z = 0.0f;
            #pragma unroll
            for (int w2 = 0; w2 < 16; ++w2) Z += scal[16 + w2];
            float invZ = 1.0f / Z;
            c0 = e0 * invZ;
            c1 = e1 * invZ;
        }

        // ---- per-thread partial s_j = c0*u[p0][j] + c1*u[p1][j] ----
        float red[32];
        #pragma unroll
        for (int k = 0; k < 16; ++k) {
            uint32_t d0 = a[k], d1 = a[16 + k];
            red[2 * k]     = fmaf(c0, f16lo(d0), c1 * f16lo(d1));
            red[2 * k + 1] = fmaf(c0, f16hi(d0), c1 * f16hi(d1));
        }
        // ---- wave reduce-scatter (31 shfl total) ----
        red_level<32, 16>(red, lane);
        red_level<16, 8>(red, lane);
        red_level<8, 4>(red, lane);
        red_level<4, 2>(red, lane);
        red_level<2, 1>(red, lane);
        red[0] += __shfl_xor(red[0], 1, 64);   // lane holds s_{lane>>1} wave-sum
        if ((lane & 1) == 0) sred[wid * 32 + (lane >> 1)] = red[0];
        __syncthreads();

        // ---- cross-wave finalize + squash (first 32 threads) ----
        if (tid < 32) {
            float sv = 0.0f;
            #pragma unroll
            for (int w2 = 0; w2 < 16; ++w2) sv += sred[w2 * 32 + tid];
            float sq = sv * sv;
            #pragma unroll
            for (int msk = 16; msk >= 1; msk >>= 1)
                sq += __shfl_xor(sq, msk, 64);
            float n = sqrtf(sq);
            float scale = sq / ((1.0f + sq) * (n + 1e-7f));
            float v = sv * scale;
            vlds[tid] = v;
            if (it == 2) out[(size_t)bs * J_ + tid] = v;
        }
        __syncthreads();

        // ---- agreement + logit update (not needed after last iter) ----
        if (it < 2) {
            const float2* vl2 = reinterpret_cast<const float2*>(vlds);
            float ag0 = 0.0f, ag1 = 0.0f;
            #pragma unroll
            for (int k = 0; k < 16; ++k) {
                float2 vk = vl2[k];               // v[2k], v[2k+1] (LDS broadcast)
                uint32_t d0 = a[k], d1 = a[16 + k];
                ag0 = fmaf(vk.x, f16lo(d0), ag0);
                ag0 = fmaf(vk.y, f16hi(d0), ag0);
                ag1 = fmaf(vk.x, f16lo(d1), ag1);
                ag1 = fmaf(vk.y, f16hi(d1), ag1);
            }
            bp0 += ag0;
            bp1 += ag1;
        }
    }
}

extern "C" void kernel_launch(void* const* d_in, const int* in_sizes, int n_in,
                              void* d_out, int out_size, void* d_ws, size_t ws_size,
                              hipStream_t stream) {
    (void)in_sizes; (void)n_in; (void)out_size;
    const float* X = (const float*)d_in[0];        // [B,P,I] fp32
    const float* W = (const float*)d_in[1];        // [S,P,J,I] fp32
    float* out     = (float*)d_out;                // [B,S,J] fp32
    uint32_t* U    = (uint32_t*)d_ws;              // fp16 u_hat [b][s][p][jp]

    const size_t need = (size_t)B_ * S_ * P_ * J_ * 2;  // 128 MiB
    if (ws_size < need) return;  // cannot run without scratch

    dim3 g1(P_ / 16, S_ / STILE);
    uhat_kernel<<<g1, 256, 0, stream>>>(W, X, U);
    routing_kernel<<<B_ * S_, 1024, 0, stream>>>(U, out);
}

// Round 18
// 114.960 us; speedup vs baseline: 1.3685x; 1.3685x over previous
//
#include <hip/hip_runtime.h>
#include <stdint.h>

#define B_ 32
#define S_ 32
#define P_ 2048
#define J_ 32
#define I_ 16
#define STILE 8

// U layout: [s][p][slot][jpair] dwords, slot = b ^ (p & 31)  (channel-
// spreading XOR swizzle). One (s,p) tile = 32 slots x 16 g = 2KB
// CONTIGUOUS; uhat writes linear NT; routing reads its b's strip at a
// p-varying slot offset -> strips spread across DRAM channels instead
// of aliasing at 2KB stride (R13's 0.76 TB/s read wall).

typedef _Float16 half8_t __attribute__((ext_vector_type(8)));
typedef float f32x16 __attribute__((ext_vector_type(16)));
typedef uint32_t u32x4 __attribute__((ext_vector_type(4)));

// fp16 unpack helpers (dword = {lo: j=2g, hi: j=2g+1} of one b-row)
__device__ inline float f16lo(uint32_t d) {
    return (float)__builtin_bit_cast(_Float16, (unsigned short)(d & 0xffffu));
}
__device__ inline float f16hi(uint32_t d) {
    return (float)__builtin_bit_cast(_Float16, (unsigned short)(d >> 16));
}

// =====================================================================
// Kernel 1 (MFMA, s-tiled): per (s,p), C[b=32,j=32] = X[b,:].W[j,:]^T.
// R13-proven fast config (NT + linear [s][p][b][g] = 31us): L2 write-
// allocate wall killed by NT; linearity keeps full-line write-combining
// (R17's 1KB-segment block-slab variant DOUBLED WRITE_SIZE - reverted).
// ONLY change vs R13: store slot = b ^ (p & 31) channel swizzle.
// X-detile, W dbuf, pack, wave-private LDS transpose: R13 verbatim.
// =====================================================================
__global__ __launch_bounds__(256) void uhat_kernel(
        const float* __restrict__ W, const float* __restrict__ X,
        uint32_t* __restrict__ U) {
    const int tid  = threadIdx.x;
    const int lane = tid & 63;
    const int wave = tid >> 6;
    const int l31  = lane & 31;
    const int lhi  = lane >> 5;       // 0/1
    const int lpar = lane & 1;        // row-parity this lane emits
    const int sb   = blockIdx.y * STILE;
    const int p0   = blockIdx.x * 16 + wave * 4;

    // wave-private transpose slab: [4 t][32 b][16 g] dwords = 8KB/wave
    __shared__ uint32_t xs[4][2048];

    // ---- X fragments: s-independent. Load + cvt ONCE. ----
    half8_t xh[4];
    #pragma unroll
    for (int t = 0; t < 4; ++t) {
        const float* xr = X + ((size_t)l31 * P_ + (p0 + t)) * I_ + lhi * 8;
        float4 x0 = *reinterpret_cast<const float4*>(xr);
        float4 x1 = *reinterpret_cast<const float4*>(xr + 4);
        xh[t][0] = (_Float16)x0.x; xh[t][1] = (_Float16)x0.y;
        xh[t][2] = (_Float16)x0.z; xh[t][3] = (_Float16)x0.w;
        xh[t][4] = (_Float16)x1.x; xh[t][5] = (_Float16)x1.y;
        xh[t][6] = (_Float16)x1.z; xh[t][7] = (_Float16)x1.w;
    }

    const int g   = l31 >> 1;         // jpair index 0..15
    const int gq  = g >> 2, ge = g & 3;
    const int Lh  = lane >> 4;        // store-phase: b sub-index
    const int tr  = (lane >> 2) & 3;  // store-phase: p-offset in wave
    const int gqr = lane & 3;         // store-phase: jp-group

    // ---- W double buffer (registers) ----
    float4 wv[2][4][2];
    #pragma unroll
    for (int t = 0; t < 4; ++t) {
        const float* wr = W + (((size_t)sb * P_ + (p0 + t)) * J_ + l31) * I_ + lhi * 8;
        wv[0][t][0] = *reinterpret_cast<const float4*>(wr);
        wv[0][t][1] = *reinterpret_cast<const float4*>(wr + 4);
    }

    #pragma unroll
    for (int ss = 0; ss < STILE; ++ss) {
        const int cur = ss & 1, nxt = cur ^ 1;
        if (ss + 1 < STILE) {         // prefetch W for s+1
            #pragma unroll
            for (int t = 0; t < 4; ++t) {
                const float* wr = W + (((size_t)(sb + ss + 1) * P_ + (p0 + t)) * J_
                                        + l31) * I_ + lhi * 8;
                wv[nxt][t][0] = *reinterpret_cast<const float4*>(wr);
                wv[nxt][t][1] = *reinterpret_cast<const float4*>(wr + 4);
            }
        }
        const int s = sb + ss;

        #pragma unroll
        for (int t = 0; t < 4; ++t) {
            half8_t Bf;
            Bf[0] = (_Float16)wv[cur][t][0].x; Bf[1] = (_Float16)wv[cur][t][0].y;
            Bf[2] = (_Float16)wv[cur][t][0].z; Bf[3] = (_Float16)wv[cur][t][0].w;
            Bf[4] = (_Float16)wv[cur][t][1].x; Bf[5] = (_Float16)wv[cur][t][1].y;
            Bf[6] = (_Float16)wv[cur][t][1].z; Bf[7] = (_Float16)wv[cur][t][1].w;

            f32x16 acc = {};
            acc = __builtin_amdgcn_mfma_f32_32x32x16_f16(xh[t], Bf, acc, 0, 0, 0);

            // pack rows (r,r+1)=(b0,b0+1) at col j=l31 into single-b dwords
            // (R9-proven) and write to swizzled wave-private LDS slab
            #pragma unroll
            for (int m = 0; m < 8; ++m) {
                const int r = 2 * m;
                uint32_t lo16 = (uint32_t)__builtin_bit_cast(
                    unsigned short, (_Float16)acc[r]);       // b0   (RNE)
                uint32_t hi16 = (uint32_t)__builtin_bit_cast(
                    unsigned short, (_Float16)acc[r + 1]);   // b0+1 (RNE)
                uint32_t hp = lo16 | (hi16 << 16);
                uint32_t tp = (uint32_t)__shfl_xor((int)hp, 1, 64);
                uint32_t d = lpar ? ((tp >> 16) | (hp & 0xffff0000u))
                                  : ((hp & 0xffffu) | (tp << 16));
                const int b = (r & 3) + lpar + 8 * (r >> 2) + 4 * lhi;
                const int k = (b >> 1) & 3;
                xs[wave][t * 512 + b * 16 + (((gq ^ k ^ t) & 3) << 2) + ge] = d;
            }
        }

        // wave-local read-back (no barrier: slab is wave-private) +
        // NT dwordx4 stores to CHANNEL-SWIZZLED slot b^(p&31): still
        // 256B-dense segments, linear per block (R13-proven geometry).
        #pragma unroll
        for (int i = 0; i < 8; ++i) {
            const int b = 4 * i + Lh;
            const int k = (b >> 1) & 3;
            const int addr = tr * 512 + b * 16 + (((gqr ^ k ^ tr) & 3) << 2);
            u32x4 vv = *reinterpret_cast<const u32x4*>(&xs[wave][addr]);
            const int p = p0 + tr;
            const int slot = b ^ (p & 31);
            __builtin_nontemporal_store(vv, reinterpret_cast<u32x4*>(
                U + (((size_t)s * P_ + p) * 32 + slot) * 16 + 4 * gqr));
        }
    }
}

// ---------- split-butterfly wave reduction of a 32-vector ----------
template <int MASK, int HALF>
__device__ inline void red_level(float* red, int lane) {
    const bool hi = (lane & MASK) != 0;
    #pragma unroll
    for (int k = 0; k < HALF; ++k) {
        float send = hi ? red[k] : red[k + HALF];
        float recv = __shfl_xor(send, MASK, 64);
        red[k] = (hi ? red[k + HALF] : red[k]) + recv;
    }
}

// =====================================================================
// Kernel 2: dynamic routing. One 1024-thread block per (b,s) — R5's
// proven body. Read-side transpose from [s][p][slot][g]: thread owns
// p-rows 2*tid, 2*tid+1; each is a 64B strip at slot b^(p&31) — the
// swizzle spreads a wave's strips across DRAM channels (R13's 2KB-
// stride aliasing was the 0.76 TB/s wall). NORMAL loads (NT loads are
// slow — R14). Partner b^1 block pinned to same XCD via h<->h+8
// swizzle: its strip is the other half of each 128B line -> L2/L3 hit
// (R13: FETCH 65MB confirmed line-dedup works).
// =====================================================================
__global__ __launch_bounds__(1024) void routing_kernel(
        const uint32_t* __restrict__ U, float* __restrict__ out) {
    const int tid  = threadIdx.x;
    const int lane = tid & 63;
    const int wid  = tid >> 6;            // 0..15

    const int h = blockIdx.x;             // 0..1023
    const int L = (h & 7) * 128 + (h >> 3);
    const int s = L >> 5;
    const int b = L & 31;

    __shared__ float sred[16 * 32];       // per-wave 32-vector partials
    __shared__ float vlds[32];
    __shared__ float scal[32];            // [0..15] max, [16..31] sum

    // load my 2 rows: 2 x 16 dwords (64B strips at swizzled slots)
    const int pA = 2 * tid, pB = 2 * tid + 1;
    const size_t baseA = (((size_t)s * P_ + pA) * 32 + (b ^ (pA & 31))) * 16;
    const size_t baseB = (((size_t)s * P_ + pB) * 32 + (b ^ (pB & 31))) * 16;
    uint32_t a[32];
    #pragma unroll
    for (int k = 0; k < 4; ++k) {
        uint4 t0 = *reinterpret_cast<const uint4*>(U + baseA + 4 * k);
        a[k * 4 + 0] = t0.x; a[k * 4 + 1] = t0.y;
        a[k * 4 + 2] = t0.z; a[k * 4 + 3] = t0.w;
        uint4 t1 = *reinterpret_cast<const uint4*>(U + baseB + 4 * k);
        a[16 + k * 4 + 0] = t1.x; a[16 + k * 4 + 1] = t1.y;
        a[16 + k * 4 + 2] = t1.z; a[16 + k * 4 + 3] = t1.w;
    }
    // a[0..15] = row pA (j-pair dwords), a[16..31] = row pB

    float bp0 = 0.0f, bp1 = 0.0f;         // routing logits for my two p's

    for (int it = 0; it < 3; ++it) {
        // ---- c = softmax(b) over p ----
        float c0, c1;
        if (it == 0) {
            c0 = c1 = 1.0f / 2048.0f;     // softmax of zeros, exact
        } else {
            float mx = fmaxf(bp0, bp1);
            #pragma unroll
            for (int msk = 32; msk >= 1; msk >>= 1)
                mx = fmaxf(mx, __shfl_xor(mx, msk, 64));
            if (lane == 0) scal[wid] = mx;
            __syncthreads();
            mx = scal[0];
            #pragma unroll
            for (int w2 = 1; w2 < 16; ++w2) mx = fmaxf(mx, scal[w2]);
            float e0 = __expf(bp0 - mx);
            float e1 = __expf(bp1 - mx);
            float zs = e0 + e1;
            #pragma unroll
            for (int msk = 32; msk >= 1; msk >>= 1)
                zs += __shfl_xor(zs, msk, 64);
            if (lane == 0) scal[16 + wid] = zs;
            __syncthreads();
            float Z = 0.0f;
            #pragma unroll
            for (int w2 = 0; w2 < 16; ++w2) Z += scal[16 + w2];
            float invZ = 1.0f / Z;
            c0 = e0 * invZ;
            c1 = e1 * invZ;
        }

        // ---- per-thread partial s_j = c0*u[pA][j] + c1*u[pB][j] ----
        float red[32];
        #pragma unroll
        for (int k = 0; k < 16; ++k) {
            uint32_t d0 = a[k], d1 = a[16 + k];
            red[2 * k]     = fmaf(c0, f16lo(d0), c1 * f16lo(d1));
            red[2 * k + 1] = fmaf(c0, f16hi(d0), c1 * f16hi(d1));
        }
        // ---- wave reduce-scatter (31 shfl total) ----
        red_level<32, 16>(red, lane);
        red_level<16, 8>(red, lane);
        red_level<8, 4>(red, lane);
        red_level<4, 2>(red, lane);
        red_level<2, 1>(red, lane);
        red[0] += __shfl_xor(red[0], 1, 64);   // lane holds s_{lane>>1} wave-sum
        if ((lane & 1) == 0) sred[wid * 32 + (lane >> 1)] = red[0];
        __syncthreads();

        // ---- cross-wave finalize + squash (first 32 threads) ----
        if (tid < 32) {
            float sv = 0.0f;
            #pragma unroll
            for (int w2 = 0; w2 < 16; ++w2) sv += sred[w2 * 32 + tid];
            float sq = sv * sv;
            #pragma unroll
            for (int msk = 16; msk >= 1; msk >>= 1)
                sq += __shfl_xor(sq, msk, 64);
            float n = sqrtf(sq);
            float scale = sq / ((1.0f + sq) * (n + 1e-7f));
            float v = sv * scale;
            vlds[tid] = v;
            if (it == 2) out[((size_t)b * S_ + s) * J_ + tid] = v;
        }
        __syncthreads();

        // ---- agreement + logit update (not needed after last iter) ----
        if (it < 2) {
            const float2* vl2 = reinterpret_cast<const float2*>(vlds);
            float ag0 = 0.0f, ag1 = 0.0f;
            #pragma unroll
            for (int k = 0; k < 16; ++k) {
                float2 vk = vl2[k];               // v[2k], v[2k+1] (LDS broadcast)
                uint32_t d0 = a[k], d1 = a[16 + k];
                ag0 = fmaf(vk.x, f16lo(d0), ag0);
                ag0 = fmaf(vk.y, f16hi(d0), ag0);
                ag1 = fmaf(vk.x, f16lo(d1), ag1);
                ag1 = fmaf(vk.y, f16hi(d1), ag1);
            }
            bp0 += ag0;
            bp1 += ag1;
        }
    }
}

extern "C" void kernel_launch(void* const* d_in, const int* in_sizes, int n_in,
                              void* d_out, int out_size, void* d_ws, size_t ws_size,
                              hipStream_t stream) {
    (void)in_sizes; (void)n_in; (void)out_size;
    const float* X = (const float*)d_in[0];        // [B,P,I] fp32
    const float* W = (const float*)d_in[1];        // [S,P,J,I] fp32
    float* out     = (float*)d_out;                // [B,S,J] fp32
    uint32_t* U    = (uint32_t*)d_ws;              // fp16 u_hat [s][p][slot][g]

    const size_t need = (size_t)B_ * S_ * P_ * J_ * 2;  // 128 MiB
    if (ws_size < need) return;  // cannot run without scratch

    dim3 g1(P_ / 16, S_ / STILE);
    uhat_kernel<<<g1, 256, 0, stream>>>(W, X, U);
    routing_kernel<<<B_ * S_, 1024, 0, stream>>>(U, out);
}

// Round 19
// 101.854 us; speedup vs baseline: 1.5446x; 1.1287x over previous
//
#include <hip/hip_runtime.h>
#include <stdint.h>

#define B_ 32
#define S_ 32
#define P_ 2048
#define J_ 32
#define I_ 16
#define STILE 8

// U layout: [s][b][p][jpair] dwords. Region (s,b) = 2048 p x 16 g =
// 128KB FULLY CONTIGUOUS (routing block reads it dense — the proven
// 22us shape). uhat writes each b-plane as a 1KB-contiguous chunk per
// block-s (4 waves x adjacent 256B NT segments) at 128KB stride —
// much coarser than R15's 256B-at-4MB-stride scatter.
#define UROW 16

typedef _Float16 half8_t __attribute__((ext_vector_type(8)));
typedef float f32x16 __attribute__((ext_vector_type(16)));
typedef uint32_t u32x4 __attribute__((ext_vector_type(4)));

// fp16 unpack helpers (dword = {lo: j=2g, hi: j=2g+1} of one b-row)
__device__ inline float f16lo(uint32_t d) {
    return (float)__builtin_bit_cast(_Float16, (unsigned short)(d & 0xffffu));
}
__device__ inline float f16hi(uint32_t d) {
    return (float)__builtin_bit_cast(_Float16, (unsigned short)(d >> 16));
}

// =====================================================================
// Kernel 1 (MFMA, s-tiled): per (s,p), C[b=32,j=32] = X[b,:].W[j,:]^T.
// Proven primitives: NT stores (kills L2 write-allocate wall, R13);
// wave-private LDS transpose -> 256B-dense segments (R10); X-detile +
// W reg-dbuf (R11). ONLY change vs R18: store address maps to
// [s][b][p][g] (no slot swizzle) -> per (b, block, s) the 4 waves'
// segments tile a 1KB-contiguous range.
// =====================================================================
__global__ __launch_bounds__(256) void uhat_kernel(
        const float* __restrict__ W, const float* __restrict__ X,
        uint32_t* __restrict__ U) {
    const int tid  = threadIdx.x;
    const int lane = tid & 63;
    const int wave = tid >> 6;
    const int l31  = lane & 31;
    const int lhi  = lane >> 5;       // 0/1
    const int lpar = lane & 1;        // row-parity this lane emits
    const int sb   = blockIdx.y * STILE;
    const int p0   = blockIdx.x * 16 + wave * 4;

    // wave-private transpose slab: [4 t][32 b][16 g] dwords = 8KB/wave
    __shared__ uint32_t xs[4][2048];

    // ---- X fragments: s-independent. Load + cvt ONCE. ----
    half8_t xh[4];
    #pragma unroll
    for (int t = 0; t < 4; ++t) {
        const float* xr = X + ((size_t)l31 * P_ + (p0 + t)) * I_ + lhi * 8;
        float4 x0 = *reinterpret_cast<const float4*>(xr);
        float4 x1 = *reinterpret_cast<const float4*>(xr + 4);
        xh[t][0] = (_Float16)x0.x; xh[t][1] = (_Float16)x0.y;
        xh[t][2] = (_Float16)x0.z; xh[t][3] = (_Float16)x0.w;
        xh[t][4] = (_Float16)x1.x; xh[t][5] = (_Float16)x1.y;
        xh[t][6] = (_Float16)x1.z; xh[t][7] = (_Float16)x1.w;
    }

    const int g   = l31 >> 1;         // jpair index 0..15
    const int gq  = g >> 2, ge = g & 3;
    const int Lh  = lane >> 4;        // store-phase: b sub-index
    const int tr  = (lane >> 2) & 3;  // store-phase: p-offset in wave
    const int gqr = lane & 3;         // store-phase: jp-group

    // ---- W double buffer (registers) ----
    float4 wv[2][4][2];
    #pragma unroll
    for (int t = 0; t < 4; ++t) {
        const float* wr = W + (((size_t)sb * P_ + (p0 + t)) * J_ + l31) * I_ + lhi * 8;
        wv[0][t][0] = *reinterpret_cast<const float4*>(wr);
        wv[0][t][1] = *reinterpret_cast<const float4*>(wr + 4);
    }

    #pragma unroll
    for (int ss = 0; ss < STILE; ++ss) {
        const int cur = ss & 1, nxt = cur ^ 1;
        if (ss + 1 < STILE) {         // prefetch W for s+1
            #pragma unroll
            for (int t = 0; t < 4; ++t) {
                const float* wr = W + (((size_t)(sb + ss + 1) * P_ + (p0 + t)) * J_
                                        + l31) * I_ + lhi * 8;
                wv[nxt][t][0] = *reinterpret_cast<const float4*>(wr);
                wv[nxt][t][1] = *reinterpret_cast<const float4*>(wr + 4);
            }
        }
        const int s = sb + ss;

        #pragma unroll
        for (int t = 0; t < 4; ++t) {
            half8_t Bf;
            Bf[0] = (_Float16)wv[cur][t][0].x; Bf[1] = (_Float16)wv[cur][t][0].y;
            Bf[2] = (_Float16)wv[cur][t][0].z; Bf[3] = (_Float16)wv[cur][t][0].w;
            Bf[4] = (_Float16)wv[cur][t][1].x; Bf[5] = (_Float16)wv[cur][t][1].y;
            Bf[6] = (_Float16)wv[cur][t][1].z; Bf[7] = (_Float16)wv[cur][t][1].w;

            f32x16 acc = {};
            acc = __builtin_amdgcn_mfma_f32_32x32x16_f16(xh[t], Bf, acc, 0, 0, 0);

            // pack rows (r,r+1)=(b0,b0+1) at col j=l31 into single-b dwords
            // (R9-proven) and write to swizzled wave-private LDS slab
            #pragma unroll
            for (int m = 0; m < 8; ++m) {
                const int r = 2 * m;
                uint32_t lo16 = (uint32_t)__builtin_bit_cast(
                    unsigned short, (_Float16)acc[r]);       // b0   (RNE)
                uint32_t hi16 = (uint32_t)__builtin_bit_cast(
                    unsigned short, (_Float16)acc[r + 1]);   // b0+1 (RNE)
                uint32_t hp = lo16 | (hi16 << 16);
                uint32_t tp = (uint32_t)__shfl_xor((int)hp, 1, 64);
                uint32_t d = lpar ? ((tp >> 16) | (hp & 0xffff0000u))
                                  : ((hp & 0xffffu) | (tp << 16));
                const int b = (r & 3) + lpar + 8 * (r >> 2) + 4 * lhi;
                const int k = (b >> 1) & 3;
                xs[wave][t * 512 + b * 16 + (((gq ^ k ^ t) & 3) << 2) + ge] = d;
            }
        }

        // wave-local read-back (no barrier: slab is wave-private) +
        // NT dwordx4 stores into [s][b][p][g]: per instr 4 b x 256B
        // dense segments; per (b, block, s) the waves tile 1KB contig.
        #pragma unroll
        for (int i = 0; i < 8; ++i) {
            const int b = 4 * i + Lh;
            const int k = (b >> 1) & 3;
            const int addr = tr * 512 + b * 16 + (((gqr ^ k ^ tr) & 3) << 2);
            u32x4 vv = *reinterpret_cast<const u32x4*>(&xs[wave][addr]);
            const int p = p0 + tr;
            __builtin_nontemporal_store(vv, reinterpret_cast<u32x4*>(
                U + (((size_t)s * 32 + b) * P_ + p) * UROW + 4 * gqr));
        }
    }
}

// ---------- split-butterfly wave reduction of a 32-vector ----------
template <int MASK, int HALF>
__device__ inline void red_level(float* red, int lane) {
    const bool hi = (lane & MASK) != 0;
    #pragma unroll
    for (int k = 0; k < HALF; ++k) {
        float send = hi ? red[k] : red[k + HALF];
        float recv = __shfl_xor(send, MASK, 64);
        red[k] = (hi ? red[k + HALF] : red[k]) + recv;
    }
}

// =====================================================================
// Kernel 2: dynamic routing. One 1024-thread block per (s,b) region —
// R5's proven ~22us body. The block's 128KB region is FULLY CONTIGUOUS
// in [s][b][p][g]; thread owns adjacent p-rows 2*tid, 2*tid+1 = 32
// dwords = 128B contiguous. NORMAL loads (NT loads slow, R14).
// blockIdx.x = s*32 + b so consecutive blocks sweep adjacent regions.
// =====================================================================
__global__ __launch_bounds__(1024) void routing_kernel(
        const uint32_t* __restrict__ U, float* __restrict__ out) {
    const int tid  = threadIdx.x;
    const int lane = tid & 63;
    const int wid  = tid >> 6;            // 0..15
    const int reg  = blockIdx.x;          // s*32 + b
    const int s    = reg >> 5;
    const int b    = reg & 31;

    __shared__ float sred[16 * 32];       // per-wave 32-vector partials
    __shared__ float vlds[32];
    __shared__ float scal[32];            // [0..15] max, [16..31] sum

    // load my 2 rows: 32 dwords = 128B contiguous (normal loads)
    const uint4* ub = reinterpret_cast<const uint4*>(
        U + (size_t)reg * ((size_t)P_ * UROW) + (size_t)tid * 32);
    uint32_t a[32];
    #pragma unroll
    for (int k = 0; k < 8; ++k) {
        uint4 t = ub[k];
        a[k * 4 + 0] = t.x; a[k * 4 + 1] = t.y;
        a[k * 4 + 2] = t.z; a[k * 4 + 3] = t.w;
    }
    // a[0..15] = row p0 (j-pair dwords), a[16..31] = row p1

    float bp0 = 0.0f, bp1 = 0.0f;         // routing logits for my two p's

    for (int it = 0; it < 3; ++it) {
        // ---- c = softmax(b) over p ----
        float c0, c1;
        if (it == 0) {
            c0 = c1 = 1.0f / 2048.0f;     // softmax of zeros, exact
        } else {
            float mx = fmaxf(bp0, bp1);
            #pragma unroll
            for (int msk = 32; msk >= 1; msk >>= 1)
                mx = fmaxf(mx, __shfl_xor(mx, msk, 64));
            if (lane == 0) scal[wid] = mx;
            __syncthreads();
            mx = scal[0];
            #pragma unroll
            for (int w2 = 1; w2 < 16; ++w2) mx = fmaxf(mx, scal[w2]);
            float e0 = __expf(bp0 - mx);
            float e1 = __expf(bp1 - mx);
            float zs = e0 + e1;
            #pragma unroll
            for (int msk = 32; msk >= 1; msk >>= 1)
                zs += __shfl_xor(zs, msk, 64);
            if (lane == 0) scal[16 + wid] = zs;
            __syncthreads();
            float Z = 0.0f;
            #pragma unroll
            for (int w2 = 0; w2 < 16; ++w2) Z += scal[16 + w2];
            float invZ = 1.0f / Z;
            c0 = e0 * invZ;
            c1 = e1 * invZ;
        }

        // ---- per-thread partial s_j = c0*u[p0][j] + c1*u[p1][j] ----
        float red[32];
        #pragma unroll
        for (int k = 0; k < 16; ++k) {
            uint32_t d0 = a[k], d1 = a[16 + k];
            red[2 * k]     = fmaf(c0, f16lo(d0), c1 * f16lo(d1));
            red[2 * k + 1] = fmaf(c0, f16hi(d0), c1 * f16hi(d1));
        }
        // ---- wave reduce-scatter (31 shfl total) ----
        red_level<32, 16>(red, lane);
        red_level<16, 8>(red, lane);
        red_level<8, 4>(red, lane);
        red_level<4, 2>(red, lane);
        red_level<2, 1>(red, lane);
        red[0] += __shfl_xor(red[0], 1, 64);   // lane holds s_{lane>>1} wave-sum
        if ((lane & 1) == 0) sred[wid * 32 + (lane >> 1)] = red[0];
        __syncthreads();

        // ---- cross-wave finalize + squash (first 32 threads) ----
        if (tid < 32) {
            float sv = 0.0f;
            #pragma unroll
            for (int w2 = 0; w2 < 16; ++w2) sv += sred[w2 * 32 + tid];
            float sq = sv * sv;
            #pragma unroll
            for (int msk = 16; msk >= 1; msk >>= 1)
                sq += __shfl_xor(sq, msk, 64);
            float n = sqrtf(sq);
            float scale = sq / ((1.0f + sq) * (n + 1e-7f));
            float v = sv * scale;
            vlds[tid] = v;
            if (it == 2) out[((size_t)b * S_ + s) * J_ + tid] = v;
        }
        __syncthreads();

        // ---- agreement + logit update (not needed after last iter) ----
        if (it < 2) {
            const float2* vl2 = reinterpret_cast<const float2*>(vlds);
            float ag0 = 0.0f, ag1 = 0.0f;
            #pragma unroll
            for (int k = 0; k < 16; ++k) {
                float2 vk = vl2[k];               // v[2k], v[2k+1] (LDS broadcast)
                uint32_t d0 = a[k], d1 = a[16 + k];
                ag0 = fmaf(vk.x, f16lo(d0), ag0);
                ag0 = fmaf(vk.y, f16hi(d0), ag0);
                ag1 = fmaf(vk.x, f16lo(d1), ag1);
                ag1 = fmaf(vk.y, f16hi(d1), ag1);
            }
            bp0 += ag0;
            bp1 += ag1;
        }
    }
}

extern "C" void kernel_launch(void* const* d_in, const int* in_sizes, int n_in,
                              void* d_out, int out_size, void* d_ws, size_t ws_size,
                              hipStream_t stream) {
    (void)in_sizes; (void)n_in; (void)out_size;
    const float* X = (const float*)d_in[0];        // [B,P,I] fp32
    const float* W = (const float*)d_in[1];        // [S,P,J,I] fp32
    float* out     = (float*)d_out;                // [B,S,J] fp32
    uint32_t* U    = (uint32_t*)d_ws;              // fp16 u_hat [s][b][p][g]

    const size_t need = (size_t)B_ * S_ * P_ * J_ * 2;  // 128 MiB
    if (ws_size < need) return;  // cannot run without scratch

    dim3 g1(P_ / 16, S_ / STILE);
    uhat_kernel<<<g1, 256, 0, stream>>>(W, X, U);
    routing_kernel<<<S_ * B_, 1024, 0, stream>>>(U, out);
}